// Round 4
// baseline (170.121 us; speedup 1.0000x reference)
//
#include <hip/hip_runtime.h>

// SupProtoConLoss on MI355X — round 15: 8-phase + XCD-resident B columns.
// League: R7 2-barrier 110.5us; R14 8-phase 107.2us (641 TF, conflicts=0 but
// FETCH 21->136MB: tm-fast sweep streamed 8MB A through each 4MB XCD L2 ->
// staging at L3 latency -> fence stalls; MfmaUtil 26% vs template's 62%).
// R15 keeps R14's schedule byte-for-byte, fixes the block->tile mapping:
//   tn = (bx&7)*4 + (idx&3)  (fast)   tm = idx>>2  (slow)
// Per XCD: 4 B-supercolumns (1 MB) L2-resident all kernel; per round 8 A
// panels (2 MB) + B = 3 MB < 4 MB L2. Staging back to L2 latency, which the
// vmcnt(4)-per-K-step pipeline covers. Stage row-bases hoisted (SALU koff).

#define NROW 8192
#define DDIM 512
#define NCLS 100
#define BKS 64    // k per K-step
#define KSTEPS 8  // DDIM / BKS

typedef float f32x4 __attribute__((ext_vector_type(4)));
typedef short s16x8 __attribute__((ext_vector_type(8)));

#define GLOBAL_AS __attribute__((address_space(1)))
#define LDS_AS __attribute__((address_space(3)))

__device__ __forceinline__ unsigned short f2bf(float x) {
  unsigned int u = __builtin_bit_cast(unsigned int, x);
  u += 0x7FFFu + ((u >> 16) & 1u);  // round-to-nearest-even
  return (unsigned short)(u >> 16);
}

// One wave per row: L2-norm, scale, cast to bf16. Also zeroes row_pos/row_neg
// (16384 floats over 2048 blocks) — k_row only touches them afterwards.
__global__ void __launch_bounds__(256) k_prep(
    const float* __restrict__ reps, float* __restrict__ row_pos,
    unsigned short* __restrict__ Rb) {
  const int wave = threadIdx.x >> 6;
  const int lane = threadIdx.x & 63;
  const int row = blockIdx.x * 4 + wave;
  if (threadIdx.x < 8) row_pos[blockIdx.x * 8 + threadIdx.x] = 0.0f;
  const float* r = reps + (size_t)row * DDIM;
  float4 v0 = *(const float4*)(r + lane * 4);
  float4 v1 = *(const float4*)(r + 256 + lane * 4);
  float ss = v0.x * v0.x + v0.y * v0.y + v0.z * v0.z + v0.w * v0.w +
             v1.x * v1.x + v1.y * v1.y + v1.z * v1.z + v1.w * v1.w;
#pragma unroll
  for (int m = 1; m < 64; m <<= 1) ss += __shfl_xor(ss, m);
  const float scale = 1.0f / sqrtf(ss);  // norms ~22.6; 1e-8 clamp unreachable
  ushort4 a, b;
  a.x = f2bf(v0.x * scale); a.y = f2bf(v0.y * scale);
  a.z = f2bf(v0.z * scale); a.w = f2bf(v0.w * scale);
  b.x = f2bf(v1.x * scale); b.y = f2bf(v1.y * scale);
  b.z = f2bf(v1.z * scale); b.w = f2bf(v1.w * scale);
  *(ushort4*)(Rb + (size_t)row * DDIM + lane * 4) = a;
  *(ushort4*)(Rb + (size_t)row * DDIM + 256 + lane * 4) = b;
}

// Block: 256x256 output tile, 8 waves as 2(M) x 4(N); wave tile 128x64 =
// acc[8][4] of 16x16x32. LDS shorts: A(buf b) at b*16384, B at 32768+b*16384.
// Half-tile = 128 rows x 64 k = 8192 shorts. Swizzle: 16B slot l of row r
// lives at physical slot l^(r&7) (both staged and read with the same XOR).
__global__ void __launch_bounds__(512, 2) k_row(
    const unsigned short* __restrict__ Rb, const int* __restrict__ labels,
    float* __restrict__ row_pos, float* __restrict__ row_neg) {
  const int bx = blockIdx.x;
  const int idx = bx >> 3;                  // 0..127 (per-XCD sequence)
  const int tn = (bx & 7) * 4 + (idx & 3);  // FAST: 4 cols pinned per XCD
  const int tm = idx >> 2;                  // SLOW: 8 panels per round
  const int i0 = tm * 256;
  const int j0 = tn * 256;

  __shared__ __attribute__((aligned(16))) unsigned short LDSH[65536];  // 128KB

  const int tid = threadIdx.x;
  const int lane = tid & 63;
  const int wave = tid >> 6;  // 0..7
  const int wr = wave >> 2, wc = wave & 3;
  const int quad = lane >> 4, c16 = lane & 15;

  // ---- staging: per-lane source permutation (involution of read-side XOR)
  const int srow = lane >> 3;                 // row-within-8 for this lane
  const int skoff = ((lane & 7) ^ srow) * 8;  // permuted 16B slot (shorts)

  // Hoisted per-lane row bases (shorts into Rb): h 0=A0,1=A1,2=B0,3=B1.
  unsigned rbase[4][2];
#pragma unroll
  for (int h = 0; h < 4; ++h) {
    const int r0 = (h < 2 ? i0 : j0) + (h & 1) * 128;
#pragma unroll
    for (int t = 0; t < 2; ++t)
      rbase[h][t] = (unsigned)(r0 + wave * 16 + t * 8 + srow) * DDIM + skoff;
  }

  // h half, kt2 = target K-step (pre-masked). 2 loads/wave.
  auto stageHalf = [&](int h, int kt2) {
    const int bb = kt2 & 1;
    const int base =
        (h < 2 ? 0 : 32768) + bb * 16384 + (h & 1) * 8192 + wave * 1024;
    const int koff = kt2 * BKS;  // SALU (kt2 wave-uniform)
#pragma unroll
    for (int t = 0; t < 2; ++t) {
      const unsigned short* src = Rb + rbase[h][t] + koff;
      __builtin_amdgcn_global_load_lds(
          (GLOBAL_AS void*)const_cast<unsigned short*>(src),
          (LDS_AS void*)(LDSH + base + t * 512), 16, 0, 0);
    }
  };

  // ---- ds_read bases (shorts). Row stride 64 shorts; swizzled slot term.
  const int x7 = c16 & 7;
  const int sp0 = ((0 * 4 + quad) ^ x7) * 8;  // ksub 0
  const int sp1 = ((1 * 4 + quad) ^ x7) * 8;  // ksub 1
  auto LD = [&](int si) { return *(const s16x8*)(LDSH + si); };

  f32x4 acc[8][4];
#pragma unroll
  for (int m = 0; m < 8; ++m)
#pragma unroll
    for (int n = 0; n < 4; ++n) acc[m][n] = (f32x4)0.0f;

  // ---- prologue: A(0),B(0) -> buf0; B(1) -> buf1. 12 loads/wave.
  stageHalf(0, 0); stageHalf(1, 0); stageHalf(2, 0); stageHalf(3, 0);
  stageHalf(2, 1); stageHalf(3, 1);
  asm volatile("s_waitcnt vmcnt(4)" ::: "memory");  // A(0)+B(0) done, B(1) fly
  __builtin_amdgcn_s_barrier();

#pragma unroll 1
  for (int kt = 0; kt < KSTEPS; ++kt) {
    const int cb = (kt & 1) * 16384;
    const int aK0 = cb + wr * 8192 + c16 * 64 + sp0;
    const int aK1 = cb + wr * 8192 + c16 * 64 + sp1;
    const int bK0 = 32768 + cb + wc * 4096 + c16 * 64 + sp0;
    const int bK1 = 32768 + cb + wc * 4096 + c16 * 64 + sp1;
    const int ktn1 = (kt + 1) & 7, ktn2 = (kt + 2) & 7;
    s16x8 aH[4][2], bF[4][2];

    // ---- phase 0: read A[mh0]+B[nh0], stage A0(kt+1), MFMA Q(0,0)
#pragma unroll
    for (int m = 0; m < 4; ++m) {
      aH[m][0] = LD(aK0 + m * 1024);
      aH[m][1] = LD(aK1 + m * 1024);
    }
#pragma unroll
    for (int n = 0; n < 2; ++n) {
      bF[n][0] = LD(bK0 + n * 1024);
      bF[n][1] = LD(bK1 + n * 1024);
    }
    stageHalf(0, ktn1);
    __builtin_amdgcn_sched_barrier(0);
    __builtin_amdgcn_s_barrier();
    __builtin_amdgcn_s_setprio(1);
#pragma unroll
    for (int m = 0; m < 4; ++m)
#pragma unroll
      for (int n = 0; n < 2; ++n) {
        acc[m][n] = __builtin_amdgcn_mfma_f32_16x16x32_bf16(aH[m][0], bF[n][0],
                                                            acc[m][n], 0, 0, 0);
        acc[m][n] = __builtin_amdgcn_mfma_f32_16x16x32_bf16(aH[m][1], bF[n][1],
                                                            acc[m][n], 0, 0, 0);
      }
    __builtin_amdgcn_s_setprio(0);
    __builtin_amdgcn_sched_barrier(0);
    __builtin_amdgcn_s_barrier();

    // ---- phase 1: read B[nh1], stage A1(kt+1), MFMA Q(0,1)
#pragma unroll
    for (int n = 2; n < 4; ++n) {
      bF[n][0] = LD(bK0 + n * 1024);
      bF[n][1] = LD(bK1 + n * 1024);
    }
    stageHalf(1, ktn1);
    __builtin_amdgcn_sched_barrier(0);
    __builtin_amdgcn_s_barrier();
    __builtin_amdgcn_s_setprio(1);
#pragma unroll
    for (int m = 0; m < 4; ++m)
#pragma unroll
      for (int n = 2; n < 4; ++n) {
        acc[m][n] = __builtin_amdgcn_mfma_f32_16x16x32_bf16(aH[m][0], bF[n][0],
                                                            acc[m][n], 0, 0, 0);
        acc[m][n] = __builtin_amdgcn_mfma_f32_16x16x32_bf16(aH[m][1], bF[n][1],
                                                            acc[m][n], 0, 0, 0);
      }
    __builtin_amdgcn_s_setprio(0);
    __builtin_amdgcn_sched_barrier(0);
    __builtin_amdgcn_s_barrier();

    // ---- phase 2: read A[mh1], stage B0(kt+2), MFMA Q(1,0)
#pragma unroll
    for (int m = 0; m < 4; ++m) {
      aH[m][0] = LD(aK0 + (m + 4) * 1024);
      aH[m][1] = LD(aK1 + (m + 4) * 1024);
    }
    stageHalf(2, ktn2);
    __builtin_amdgcn_sched_barrier(0);
    __builtin_amdgcn_s_barrier();
    __builtin_amdgcn_s_setprio(1);
#pragma unroll
    for (int m = 0; m < 4; ++m)
#pragma unroll
      for (int n = 0; n < 2; ++n) {
        acc[m + 4][n] = __builtin_amdgcn_mfma_f32_16x16x32_bf16(
            aH[m][0], bF[n][0], acc[m + 4][n], 0, 0, 0);
        acc[m + 4][n] = __builtin_amdgcn_mfma_f32_16x16x32_bf16(
            aH[m][1], bF[n][1], acc[m + 4][n], 0, 0, 0);
      }
    __builtin_amdgcn_s_setprio(0);
    __builtin_amdgcn_sched_barrier(0);
    __builtin_amdgcn_s_barrier();

    // ---- phase 3: stage B1(kt+2), MFMA Q(1,1), then the K-step fence:
    // vmcnt(4) BEFORE the barrier => all waves' A(kt+1)/B(kt+1) DMAs landed.
    stageHalf(3, ktn2);
    __builtin_amdgcn_sched_barrier(0);
    __builtin_amdgcn_s_barrier();
    __builtin_amdgcn_s_setprio(1);
#pragma unroll
    for (int m = 0; m < 4; ++m)
#pragma unroll
      for (int n = 2; n < 4; ++n) {
        acc[m + 4][n] = __builtin_amdgcn_mfma_f32_16x16x32_bf16(
            aH[m][0], bF[n][0], acc[m + 4][n], 0, 0, 0);
        acc[m + 4][n] = __builtin_amdgcn_mfma_f32_16x16x32_bf16(
            aH[m][1], bF[n][1], acc[m + 4][n], 0, 0, 0);
      }
    __builtin_amdgcn_s_setprio(0);
    __builtin_amdgcn_sched_barrier(0);
    asm volatile("s_waitcnt vmcnt(4)" ::: "memory");
    __builtin_amdgcn_s_barrier();
  }

  // ---- epilogue: fold + row reduction, once per block.
  __syncthreads();  // drains remaining DMAs -> LDS reusable
  float* rp = (float*)&LDSH[0];  // 256 floats
  float* rn = rp + 256;
  ((float*)&LDSH[0])[tid] = 0.0f;  // tid<512 zeroes rp+rn exactly
  __syncthreads();

  const float C0 = -5.0f + 1e-7f;  // s = 5g - 5 + 1e-7 (static shift S=10)
  int lj[4], gj4[4];
#pragma unroll
  for (int n = 0; n < 4; ++n) {
    gj4[n] = j0 + wc * 64 + n * 16 + c16;
    lj[n] = labels[gj4[n]];
  }
#pragma unroll
  for (int m = 0; m < 8; ++m) {
#pragma unroll
    for (int r = 0; r < 4; ++r) {
      const int lrow = wr * 128 + m * 16 + quad * 4 + r;
      const int gi = i0 + lrow;
      const int li = labels[gi];
      float ps = 0.0f, ns = 0.0f;
#pragma unroll
      for (int n = 0; n < 4; ++n) {
        const float g = acc[m][n][r];
        const float sv = fmaf(g, 5.0f, C0);
        const float ev = __expf(sv);
        const bool same = (li == lj[n]);
        ps += (same && gi != gj4[n]) ? sv : 0.0f;
        ns += same ? 0.0f : ev;
      }
#pragma unroll
      for (int mm = 1; mm < 16; mm <<= 1) {  // reduce across the 16 c16 lanes
        ps += __shfl_xor(ps, mm);
        ns += __shfl_xor(ns, mm);
      }
      if (c16 == 0) {  // 4 wc-waves contend per address, once per block
        atomicAdd(&rp[lrow], ps);
        atomicAdd(&rn[lrow], ns);
      }
    }
  }
  __syncthreads();
  if (tid < 256) {
    atomicAdd(&row_pos[i0 + tid], rp[tid]);  // 32 adds per address chip-wide
    atomicAdd(&row_neg[i0 + tid], rn[tid]);
  }
}

// LDS label histogram + loss reduction (cnt array eliminated).
__global__ void __launch_bounds__(512) k_final(
    const float* __restrict__ row_pos, const float* __restrict__ row_neg,
    const int* __restrict__ labels, float* __restrict__ out) {
  __shared__ int hcnt[NCLS];
  __shared__ float ssum[8];
  __shared__ float scnt[8];
  const int tid = threadIdx.x;
  if (tid < NCLS) hcnt[tid] = 0;
  __syncthreads();
  for (int i = tid; i < NROW; i += 512) atomicAdd(&hcnt[labels[i]], 1);
  __syncthreads();
  float lsum = 0.0f, lcnt = 0.0f;
  for (int i = tid; i < NROW; i += 512) {
    const float c = (float)(hcnt[labels[i]] - 1);
    const float pos = row_pos[i] / (c + 1e-8f);
    const float loss = -pos + logf(row_neg[i] + 1e-8f);
    if (loss > 0.0f) { lsum += loss; lcnt += 1.0f; }
  }
#pragma unroll
  for (int m = 1; m < 64; m <<= 1) {
    lsum += __shfl_xor(lsum, m);
    lcnt += __shfl_xor(lcnt, m);
  }
  if ((tid & 63) == 0) { ssum[tid >> 6] = lsum; scnt[tid >> 6] = lcnt; }
  __syncthreads();
  if (tid == 0) {
    float S = 0.0f, C = 0.0f;
#pragma unroll
    for (int w = 0; w < 8; ++w) { S += ssum[w]; C += scnt[w]; }
    out[0] = S / (C + 1e-8f);
  }
}

extern "C" void kernel_launch(void* const* d_in, const int* in_sizes, int n_in,
                              void* d_out, int out_size, void* d_ws, size_t ws_size,
                              hipStream_t stream) {
  const float* reps = (const float*)d_in[0];
  const int* labels = (const int*)d_in[1];
  float* out = (float*)d_out;
  char* ws = (char*)d_ws;
  // ws layout: Rb (bf16 normalized reps, 8 MiB) | row_pos | row_neg
  unsigned short* Rb = (unsigned short*)ws;
  float* row_pos = (float*)(ws + (size_t)NROW * DDIM * 2);
  float* row_neg = row_pos + NROW;

  k_prep<<<NROW / 4, 256, 0, stream>>>(reps, row_pos, Rb);
  k_row<<<1024, 512, 0, stream>>>(Rb, labels, row_pos, row_neg);
  k_final<<<1, 512, 0, stream>>>(row_pos, row_neg, labels, out);
  (void)in_sizes; (void)n_in; (void)out_size; (void)ws_size;
}

// Round 5
// 147.542 us; speedup vs baseline: 1.1530x; 1.1530x over previous
//
#include <hip/hip_runtime.h>

// SupProtoConLoss on MI355X — round 16: SYMMETRY (2x FLOP cut) + 4 blocks/CU.
// League: R7 110.5; R14/R15 8-phase 107.5 (conflicts 0, FETCH fixed 136->33MB
// with ZERO time delta => not DMA-bound; stuck 26% MfmaUtil = barrier lockstep
// at 2 waves/SIMD, no TLP possible at 256^2 since acc=128 AGPR).
// R16: gram is symmetric -> upper-triangle panel tiles only (2080 of 128^2),
// fold each off-diag tile into BOTH row-i (reduce over cols) and row-j
// (reduce over rows) sums; diagonal tiles fold one-sided with gi!=gj mask.
//   - 128^2 tile, 4 waves (wave tile 64x64, acc[4][4]=64 AGPR), BK=32,
//     dbuf LDS 32 KB, launch_bounds(256,4) -> 4 blocks/CU, 16 waves/CU:
//     independent-block drift hides barrier drains (m114 mechanism).
//   - frag reads slot-XOR swizzled (4-way residual conflict, accepted).
//   - early-stage covered drain (R11), 16 K-steps.

#define NROW 8192
#define DDIM 512
#define NCLS 100
#define TILE 128
#define BK 32
#define NKS 16    // DDIM / BK
#define NPAN 64   // NROW / TILE
#define NTRI 2080  // NPAN*(NPAN+1)/2

typedef float f32x4 __attribute__((ext_vector_type(4)));
typedef short s16x8 __attribute__((ext_vector_type(8)));

#define GLOBAL_AS __attribute__((address_space(1)))
#define LDS_AS __attribute__((address_space(3)))

__device__ __forceinline__ unsigned short f2bf(float x) {
  unsigned int u = __builtin_bit_cast(unsigned int, x);
  u += 0x7FFFu + ((u >> 16) & 1u);  // round-to-nearest-even
  return (unsigned short)(u >> 16);
}

// One wave per row: L2-norm, scale, cast to bf16. Also zeroes row_pos/row_neg
// (16384 floats over 2048 blocks) — k_row only touches them afterwards.
__global__ void __launch_bounds__(256) k_prep(
    const float* __restrict__ reps, float* __restrict__ row_pos,
    unsigned short* __restrict__ Rb) {
  const int wave = threadIdx.x >> 6;
  const int lane = threadIdx.x & 63;
  const int row = blockIdx.x * 4 + wave;
  if (threadIdx.x < 8) row_pos[blockIdx.x * 8 + threadIdx.x] = 0.0f;
  const float* r = reps + (size_t)row * DDIM;
  float4 v0 = *(const float4*)(r + lane * 4);
  float4 v1 = *(const float4*)(r + 256 + lane * 4);
  float ss = v0.x * v0.x + v0.y * v0.y + v0.z * v0.z + v0.w * v0.w +
             v1.x * v1.x + v1.y * v1.y + v1.z * v1.z + v1.w * v1.w;
#pragma unroll
  for (int m = 1; m < 64; m <<= 1) ss += __shfl_xor(ss, m);
  const float scale = 1.0f / sqrtf(ss);  // norms ~22.6; 1e-8 clamp unreachable
  ushort4 a, b;
  a.x = f2bf(v0.x * scale); a.y = f2bf(v0.y * scale);
  a.z = f2bf(v0.z * scale); a.w = f2bf(v0.w * scale);
  b.x = f2bf(v1.x * scale); b.y = f2bf(v1.y * scale);
  b.z = f2bf(v1.z * scale); b.w = f2bf(v1.w * scale);
  *(ushort4*)(Rb + (size_t)row * DDIM + lane * 4) = a;
  *(ushort4*)(Rb + (size_t)row * DDIM + 256 + lane * 4) = b;
}

// Block = one upper-triangle 128x128 tile (tm <= tn). 4 waves as 2M x 2N;
// wave tile 64x64 = acc[4][4] of 16x16x32. LDS [buf][mat][row][BK], row
// stride 64 B; 16B slot s of row r stored at phys slot s^(r&3) (both sides).
__global__ void __launch_bounds__(256, 4) k_row(
    const unsigned short* __restrict__ Rb, const int* __restrict__ labels,
    float* __restrict__ row_pos, float* __restrict__ row_neg) {
  const int t = blockIdx.x;
  int tn = (int)((sqrtf(8.0f * (float)t + 1.0f) - 1.0f) * 0.5f);
  while ((tn + 1) * (tn + 2) / 2 <= t) ++tn;
  while (tn * (tn + 1) / 2 > t) --tn;
  const int tm = t - tn * (tn + 1) / 2;  // 0..tn
  const int i0 = tm * TILE;              // row panel
  const int j0 = tn * TILE;              // col panel, j0 >= i0
  const bool diag = (tm == tn);

  __shared__ __attribute__((aligned(16))) unsigned short LDSH[2][2][TILE][BK];
  unsigned short* LF = &LDSH[0][0][0][0];

  const int tid = threadIdx.x;
  const int lane = tid & 63;
  const int wave = tid >> 6;  // 0..3
  const int wr = wave >> 1, wc = wave & 1;
  const int quad = lane >> 4, c16 = lane & 15;

  // Staging: unit u (16B) -> LDS offset u*16 (linear dest); row = u>>2,
  // phys slot = u&3 -> source slot (u&3)^(row&3) (pre-permuted source).
  unsigned sb[2][2];  // [mat][t] per-lane source base (shorts)
#pragma unroll
  for (int mt = 0; mt < 2; ++mt) {
    const int r0 = mt ? j0 : i0;
#pragma unroll
    for (int tt = 0; tt < 2; ++tt) {
      const unsigned u = wave * 128 + tt * 64 + lane;
      sb[mt][tt] =
          (unsigned)(r0 + (u >> 2)) * DDIM + (((u & 3) ^ ((u >> 2) & 3)) * 8);
    }
  }

  auto stage = [&](int kt, int bb) {
    const int koff = kt * BK;
#pragma unroll
    for (int mt = 0; mt < 2; ++mt)
#pragma unroll
      for (int tt = 0; tt < 2; ++tt) {
        const unsigned short* src = Rb + sb[mt][tt] + koff;
        __builtin_amdgcn_global_load_lds(
            (GLOBAL_AS void*)const_cast<unsigned short*>(src),
            (LDS_AS void*)(LF + bb * 8192 + mt * 4096 +
                           (wave * 128 + tt * 64) * 8),
            16, 0, 0);
      }
  };

  // Frag read bases (shorts). row&3 == c16&3 for all m/n -> xslot hoists.
  const int xs = (quad ^ (c16 & 3)) * 8;
  const int aBase = (wr * 64 + c16) * 32 + xs;
  const int bBase = 4096 + (wc * 64 + c16) * 32 + xs;

  f32x4 acc[4][4];
#pragma unroll
  for (int m = 0; m < 4; ++m)
#pragma unroll
    for (int n = 0; n < 4; ++n) acc[m][n] = (f32x4)0.0f;

  stage(0, 0);
  __syncthreads();

#pragma unroll 2
  for (int kt = 0; kt < NKS; ++kt) {
    const int cur = kt & 1;
    if (kt < NKS - 1) stage(kt + 1, cur ^ 1);  // ~full K-step to land
    const int cb = cur * 8192;
    s16x8 af[4], bf[4];
#pragma unroll
    for (int m = 0; m < 4; ++m)
      af[m] = *(const s16x8*)(LF + cb + aBase + m * 512);
#pragma unroll
    for (int n = 0; n < 4; ++n)
      bf[n] = *(const s16x8*)(LF + cb + bBase + n * 512);
#pragma unroll
    for (int m = 0; m < 4; ++m)
#pragma unroll
      for (int n = 0; n < 4; ++n)
        acc[m][n] = __builtin_amdgcn_mfma_f32_16x16x32_bf16(af[m], bf[n],
                                                            acc[m][n], 0, 0, 0);
    __syncthreads();  // drains stage(kt+1) DMAs + read hazard for buf swap
  }

  // ---- Epilogue: fold tile into row-i sums and (off-diag) row-j sums.
  float* rp = (float*)LF;  // 128 row-pos | 128 row-neg | 128 col-pos | 128 col-neg
  float* rn = rp + 128;
  float* cp = rn + 128;
  float* cn = cp + 128;
  rp[tid] = 0.0f;
  rp[tid + 256] = 0.0f;
  __syncthreads();

  const float C0 = -5.0f + 1e-7f;  // s = 5g - 5 + 1e-7 (static shift S=10)
  int lj4[4], gj4[4];
#pragma unroll
  for (int n = 0; n < 4; ++n) {
    gj4[n] = j0 + wc * 64 + n * 16 + c16;
    lj4[n] = labels[gj4[n]];
  }
  float psj[4] = {0.0f, 0.0f, 0.0f, 0.0f};
  float nsj[4] = {0.0f, 0.0f, 0.0f, 0.0f};
#pragma unroll
  for (int m = 0; m < 4; ++m) {
#pragma unroll
    for (int r = 0; r < 4; ++r) {
      const int lrow = wr * 64 + m * 16 + quad * 4 + r;
      const int gi = i0 + lrow;
      const int li = labels[gi];
      float psi = 0.0f, nsi = 0.0f;
#pragma unroll
      for (int n = 0; n < 4; ++n) {
        const float g = acc[m][n][r];
        const float sv = fmaf(g, 5.0f, C0);
        const float ev = __expf(sv);
        const bool same = (li == lj4[n]);
        const bool ok = same && (gi != gj4[n]);
        psi += ok ? sv : 0.0f;
        nsi += same ? 0.0f : ev;
        psj[n] += ok ? sv : 0.0f;  // col-side accumulation (over m,r)
        nsj[n] += same ? 0.0f : ev;
      }
#pragma unroll
      for (int s = 1; s < 16; s <<= 1) {  // reduce over the 16 c16 lanes
        psi += __shfl_xor(psi, s);
        nsi += __shfl_xor(nsi, s);
      }
      if (c16 == 0) {
        atomicAdd(&rp[lrow], psi);
        atomicAdd(&rn[lrow], nsi);
      }
    }
  }
  if (!diag) {  // col-side: reduce over quad groups, cross-wr via LDS atomics
#pragma unroll
    for (int n = 0; n < 4; ++n) {
      float p = psj[n], q = nsj[n];
      p += __shfl_xor(p, 16); p += __shfl_xor(p, 32);
      q += __shfl_xor(q, 16); q += __shfl_xor(q, 32);
      if (quad == 0) {
        atomicAdd(&cp[wc * 64 + n * 16 + c16], p);
        atomicAdd(&cn[wc * 64 + n * 16 + c16], q);
      }
    }
  }
  __syncthreads();
  if (tid < 128) {
    atomicAdd(&row_pos[i0 + tid], rp[tid]);
    atomicAdd(&row_neg[i0 + tid], rn[tid]);
  } else if (!diag) {
    atomicAdd(&row_pos[j0 + tid - 128], cp[tid - 128]);
    atomicAdd(&row_neg[j0 + tid - 128], cn[tid - 128]);
  }
}

// LDS label histogram + loss reduction (cnt array eliminated).
__global__ void __launch_bounds__(512) k_final(
    const float* __restrict__ row_pos, const float* __restrict__ row_neg,
    const int* __restrict__ labels, float* __restrict__ out) {
  __shared__ int hcnt[NCLS];
  __shared__ float ssum[8];
  __shared__ float scnt[8];
  const int tid = threadIdx.x;
  if (tid < NCLS) hcnt[tid] = 0;
  __syncthreads();
  for (int i = tid; i < NROW; i += 512) atomicAdd(&hcnt[labels[i]], 1);
  __syncthreads();
  float lsum = 0.0f, lcnt = 0.0f;
  for (int i = tid; i < NROW; i += 512) {
    const float c = (float)(hcnt[labels[i]] - 1);
    const float pos = row_pos[i] / (c + 1e-8f);
    const float loss = -pos + logf(row_neg[i] + 1e-8f);
    if (loss > 0.0f) { lsum += loss; lcnt += 1.0f; }
  }
#pragma unroll
  for (int m = 1; m < 64; m <<= 1) {
    lsum += __shfl_xor(lsum, m);
    lcnt += __shfl_xor(lcnt, m);
  }
  if ((tid & 63) == 0) { ssum[tid >> 6] = lsum; scnt[tid >> 6] = lcnt; }
  __syncthreads();
  if (tid == 0) {
    float S = 0.0f, C = 0.0f;
#pragma unroll
    for (int w = 0; w < 8; ++w) { S += ssum[w]; C += scnt[w]; }
    out[0] = S / (C + 1e-8f);
  }
}

extern "C" void kernel_launch(void* const* d_in, const int* in_sizes, int n_in,
                              void* d_out, int out_size, void* d_ws, size_t ws_size,
                              hipStream_t stream) {
  const float* reps = (const float*)d_in[0];
  const int* labels = (const int*)d_in[1];
  float* out = (float*)d_out;
  char* ws = (char*)d_ws;
  // ws layout: Rb (bf16 normalized reps, 8 MiB) | row_pos | row_neg
  unsigned short* Rb = (unsigned short*)ws;
  float* row_pos = (float*)(ws + (size_t)NROW * DDIM * 2);
  float* row_neg = row_pos + NROW;

  k_prep<<<NROW / 4, 256, 0, stream>>>(reps, row_pos, Rb);
  k_row<<<NTRI, 256, 0, stream>>>(Rb, labels, row_pos, row_neg);
  k_final<<<1, 512, 0, stream>>>(row_pos, row_neg, labels, out);
  (void)in_sizes; (void)n_in; (void)out_size; (void)ws_size;
}

// Round 6
// 142.478 us; speedup vs baseline: 1.1940x; 1.0355x over previous
//
#include <hip/hip_runtime.h>

// SupProtoConLoss on MI355X — round 17: R16 + triple-buffer counted-vmcnt.
// League: R15 8-phase 107.5; R16 symmetry 78.9 (total 147.5). R16 post-mortem:
// LDS at 26% BW (not the limit); loop's __syncthreads drains vmcnt(0) ->
// exposes DMA latency (FETCH 96MB => much of staging at HBM ~900cy) every
// iter => 17.6% MfmaUtil, latency-bound. R17 applies T4 to the triangle
// kernel: 3 x 16KB LDS bufs, stage(kt+2) issued at iter kt, vmcnt(4) before
// a RAW s_barrier (stage(kt+1) landed, kt+2 still flying) -> DMAs get ~2
// iters + 3-blocks/CU TLP to land. Tail iters drain vmcnt(0). Everything
// else (swizzle, setprio, fold-both-sides epilogue, triangle map) = R16.

#define NROW 8192
#define DDIM 512
#define NCLS 100
#define TILE 128
#define BK 32
#define NKS 16     // DDIM / BK
#define NPAN 64    // NROW / TILE
#define NTRI 2080  // NPAN*(NPAN+1)/2

typedef float f32x4 __attribute__((ext_vector_type(4)));
typedef short s16x8 __attribute__((ext_vector_type(8)));

#define GLOBAL_AS __attribute__((address_space(1)))
#define LDS_AS __attribute__((address_space(3)))

__device__ __forceinline__ unsigned short f2bf(float x) {
  unsigned int u = __builtin_bit_cast(unsigned int, x);
  u += 0x7FFFu + ((u >> 16) & 1u);  // round-to-nearest-even
  return (unsigned short)(u >> 16);
}

// One wave per row: L2-norm, scale, cast to bf16. Also zeroes row_pos/row_neg
// (16384 floats over 2048 blocks) — k_row only touches them afterwards.
__global__ void __launch_bounds__(256) k_prep(
    const float* __restrict__ reps, float* __restrict__ row_pos,
    unsigned short* __restrict__ Rb) {
  const int wave = threadIdx.x >> 6;
  const int lane = threadIdx.x & 63;
  const int row = blockIdx.x * 4 + wave;
  if (threadIdx.x < 8) row_pos[blockIdx.x * 8 + threadIdx.x] = 0.0f;
  const float* r = reps + (size_t)row * DDIM;
  float4 v0 = *(const float4*)(r + lane * 4);
  float4 v1 = *(const float4*)(r + 256 + lane * 4);
  float ss = v0.x * v0.x + v0.y * v0.y + v0.z * v0.z + v0.w * v0.w +
             v1.x * v1.x + v1.y * v1.y + v1.z * v1.z + v1.w * v1.w;
#pragma unroll
  for (int m = 1; m < 64; m <<= 1) ss += __shfl_xor(ss, m);
  const float scale = 1.0f / sqrtf(ss);  // norms ~22.6; 1e-8 clamp unreachable
  ushort4 a, b;
  a.x = f2bf(v0.x * scale); a.y = f2bf(v0.y * scale);
  a.z = f2bf(v0.z * scale); a.w = f2bf(v0.w * scale);
  b.x = f2bf(v1.x * scale); b.y = f2bf(v1.y * scale);
  b.z = f2bf(v1.z * scale); b.w = f2bf(v1.w * scale);
  *(ushort4*)(Rb + (size_t)row * DDIM + lane * 4) = a;
  *(ushort4*)(Rb + (size_t)row * DDIM + 256 + lane * 4) = b;
}

// Block = one upper-triangle 128x128 tile (tm <= tn). 4 waves as 2M x 2N;
// wave tile 64x64 = acc[4][4] of 16x16x32. LDS [buf3][mat][row][BK], row
// stride 64 B; 16B slot s of row r stored at phys slot s^(r&3) (both sides).
__global__ void __launch_bounds__(256, 3) k_row(
    const unsigned short* __restrict__ Rb, const int* __restrict__ labels,
    float* __restrict__ row_pos, float* __restrict__ row_neg) {
  const int t = blockIdx.x;
  int tn = (int)((sqrtf(8.0f * (float)t + 1.0f) - 1.0f) * 0.5f);
  while ((tn + 1) * (tn + 2) / 2 <= t) ++tn;
  while (tn * (tn + 1) / 2 > t) --tn;
  const int tm = t - tn * (tn + 1) / 2;  // 0..tn
  const int i0 = tm * TILE;              // row panel
  const int j0 = tn * TILE;              // col panel, j0 >= i0
  const bool diag = (tm == tn);

  __shared__ __attribute__((aligned(16))) unsigned short LDSH[3][2][TILE][BK];
  unsigned short* LF = &LDSH[0][0][0][0];

  const int tid = threadIdx.x;
  const int lane = tid & 63;
  const int wave = tid >> 6;  // 0..3
  const int wr = wave >> 1, wc = wave & 1;
  const int quad = lane >> 4, c16 = lane & 15;

  // Staging: unit u (16B) -> LDS offset u*16 (linear dest); row = u>>2,
  // phys slot = u&3 -> source slot (u&3)^(row&3) (pre-permuted source).
  unsigned sb[2][2];  // [mat][t] per-lane source base (shorts)
#pragma unroll
  for (int mt = 0; mt < 2; ++mt) {
    const int r0 = mt ? j0 : i0;
#pragma unroll
    for (int tt = 0; tt < 2; ++tt) {
      const unsigned u = wave * 128 + tt * 64 + lane;
      sb[mt][tt] =
          (unsigned)(r0 + (u >> 2)) * DDIM + (((u & 3) ^ ((u >> 2) & 3)) * 8);
    }
  }

  // 4 DMA loads per wave per call (the vmcnt ledger unit).
  auto stage = [&](int kt, int bb) {
    const int koff = kt * BK;
#pragma unroll
    for (int mt = 0; mt < 2; ++mt)
#pragma unroll
      for (int tt = 0; tt < 2; ++tt) {
        const unsigned short* src = Rb + sb[mt][tt] + koff;
        __builtin_amdgcn_global_load_lds(
            (GLOBAL_AS void*)const_cast<unsigned short*>(src),
            (LDS_AS void*)(LF + bb * 8192 + mt * 4096 +
                           (wave * 128 + tt * 64) * 8),
            16, 0, 0);
      }
  };

  // Frag read bases (shorts). row&3 == c16&3 for all m/n -> xslot hoists.
  const int xs = (quad ^ (c16 & 3)) * 8;
  const int aBase = (wr * 64 + c16) * 32 + xs;
  const int bBase = 4096 + (wc * 64 + c16) * 32 + xs;

  f32x4 acc[4][4];
#pragma unroll
  for (int m = 0; m < 4; ++m)
#pragma unroll
    for (int n = 0; n < 4; ++n) acc[m][n] = (f32x4)0.0f;

  // Prologue: buf0 <- kt0, buf1 <- kt1; wait kt0 only (kt1 stays in flight).
  stage(0, 0);
  stage(1, 1);
  asm volatile("s_waitcnt vmcnt(4)" ::: "memory");
  __builtin_amdgcn_s_barrier();

  int cur = 0, stq = 2;
#pragma unroll 1
  for (int kt = 0; kt < NKS; ++kt) {
    if (kt + 2 < NKS) stage(kt + 2, stq);  // distance-2 prefetch
    const int cb = cur * 8192;
    s16x8 af[4], bf[4];
#pragma unroll
    for (int m = 0; m < 4; ++m)
      af[m] = *(const s16x8*)(LF + cb + aBase + m * 512);
#pragma unroll
    for (int n = 0; n < 4; ++n)
      bf[n] = *(const s16x8*)(LF + cb + bBase + n * 512);
    __builtin_amdgcn_s_setprio(1);
#pragma unroll
    for (int m = 0; m < 4; ++m)
#pragma unroll
      for (int n = 0; n < 4; ++n)
        acc[m][n] = __builtin_amdgcn_mfma_f32_16x16x32_bf16(af[m], bf[n],
                                                            acc[m][n], 0, 0, 0);
    __builtin_amdgcn_s_setprio(0);
    __builtin_amdgcn_sched_barrier(0);
    // Counted fence: own stage(kt+1) landed; stage(kt+2) still in flight.
    // After the barrier, ALL waves' stage(kt+1) DMAs have landed.
    if (kt < NKS - 2) {
      asm volatile("s_waitcnt vmcnt(4)" ::: "memory");
    } else {
      asm volatile("s_waitcnt vmcnt(0)" ::: "memory");
    }
    __builtin_amdgcn_s_barrier();
    cur = cur == 2 ? 0 : cur + 1;
    stq = stq == 2 ? 0 : stq + 1;
  }

  // ---- Epilogue: fold tile into row-i sums and (off-diag) row-j sums.
  // (final loop iter ended with vmcnt(0)+barrier -> LDS reusable now)
  float* rp = (float*)LF;  // 128 row-pos | 128 row-neg | 128 col-pos | col-neg
  float* rn = rp + 128;
  float* cp = rn + 128;
  float* cn = cp + 128;
  rp[tid] = 0.0f;
  rp[tid + 256] = 0.0f;
  __syncthreads();

  const float C0 = -5.0f + 1e-7f;  // s = 5g - 5 + 1e-7 (static shift S=10)
  int lj4[4], gj4[4];
#pragma unroll
  for (int n = 0; n < 4; ++n) {
    gj4[n] = j0 + wc * 64 + n * 16 + c16;
    lj4[n] = labels[gj4[n]];
  }
  float psj[4] = {0.0f, 0.0f, 0.0f, 0.0f};
  float nsj[4] = {0.0f, 0.0f, 0.0f, 0.0f};
#pragma unroll
  for (int m = 0; m < 4; ++m) {
#pragma unroll
    for (int r = 0; r < 4; ++r) {
      const int lrow = wr * 64 + m * 16 + quad * 4 + r;
      const int gi = i0 + lrow;
      const int li = labels[gi];
      float psi = 0.0f, nsi = 0.0f;
#pragma unroll
      for (int n = 0; n < 4; ++n) {
        const float g = acc[m][n][r];
        const float sv = fmaf(g, 5.0f, C0);
        const float ev = __expf(sv);
        const bool same = (li == lj4[n]);
        const bool ok = same && (gi != gj4[n]);
        psi += ok ? sv : 0.0f;
        nsi += same ? 0.0f : ev;
        psj[n] += ok ? sv : 0.0f;  // col-side accumulation (over m,r)
        nsj[n] += same ? 0.0f : ev;
      }
#pragma unroll
      for (int s = 1; s < 16; s <<= 1) {  // reduce over the 16 c16 lanes
        psi += __shfl_xor(psi, s);
        nsi += __shfl_xor(nsi, s);
      }
      if (c16 == 0) {
        atomicAdd(&rp[lrow], psi);
        atomicAdd(&rn[lrow], nsi);
      }
    }
  }
  if (!diag) {  // col-side: reduce over quad groups, cross-wr via LDS atomics
#pragma unroll
    for (int n = 0; n < 4; ++n) {
      float p = psj[n], q = nsj[n];
      p += __shfl_xor(p, 16); p += __shfl_xor(p, 32);
      q += __shfl_xor(q, 16); q += __shfl_xor(q, 32);
      if (quad == 0) {
        atomicAdd(&cp[wc * 64 + n * 16 + c16], p);
        atomicAdd(&cn[wc * 64 + n * 16 + c16], q);
      }
    }
  }
  __syncthreads();
  if (tid < 128) {
    atomicAdd(&row_pos[i0 + tid], rp[tid]);
    atomicAdd(&row_neg[i0 + tid], rn[tid]);
  } else if (!diag) {
    atomicAdd(&row_pos[j0 + tid - 128], cp[tid - 128]);
    atomicAdd(&row_neg[j0 + tid - 128], cn[tid - 128]);
  }
}

// LDS label histogram + loss reduction (cnt array eliminated).
__global__ void __launch_bounds__(512) k_final(
    const float* __restrict__ row_pos, const float* __restrict__ row_neg,
    const int* __restrict__ labels, float* __restrict__ out) {
  __shared__ int hcnt[NCLS];
  __shared__ float ssum[8];
  __shared__ float scnt[8];
  const int tid = threadIdx.x;
  if (tid < NCLS) hcnt[tid] = 0;
  __syncthreads();
  for (int i = tid; i < NROW; i += 512) atomicAdd(&hcnt[labels[i]], 1);
  __syncthreads();
  float lsum = 0.0f, lcnt = 0.0f;
  for (int i = tid; i < NROW; i += 512) {
    const float c = (float)(hcnt[labels[i]] - 1);
    const float pos = row_pos[i] / (c + 1e-8f);
    const float loss = -pos + logf(row_neg[i] + 1e-8f);
    if (loss > 0.0f) { lsum += loss; lcnt += 1.0f; }
  }
#pragma unroll
  for (int m = 1; m < 64; m <<= 1) {
    lsum += __shfl_xor(lsum, m);
    lcnt += __shfl_xor(lcnt, m);
  }
  if ((tid & 63) == 0) { ssum[tid >> 6] = lsum; scnt[tid >> 6] = lcnt; }
  __syncthreads();
  if (tid == 0) {
    float S = 0.0f, C = 0.0f;
#pragma unroll
    for (int w = 0; w < 8; ++w) { S += ssum[w]; C += scnt[w]; }
    out[0] = S / (C + 1e-8f);
  }
}

extern "C" void kernel_launch(void* const* d_in, const int* in_sizes, int n_in,
                              void* d_out, int out_size, void* d_ws, size_t ws_size,
                              hipStream_t stream) {
  const float* reps = (const float*)d_in[0];
  const int* labels = (const int*)d_in[1];
  float* out = (float*)d_out;
  char* ws = (char*)d_ws;
  // ws layout: Rb (bf16 normalized reps, 8 MiB) | row_pos | row_neg
  unsigned short* Rb = (unsigned short*)ws;
  float* row_pos = (float*)(ws + (size_t)NROW * DDIM * 2);
  float* row_neg = row_pos + NROW;

  k_prep<<<NROW / 4, 256, 0, stream>>>(reps, row_pos, Rb);
  k_row<<<NTRI, 256, 0, stream>>>(Rb, labels, row_pos, row_neg);
  k_final<<<1, 512, 0, stream>>>(row_pos, row_neg, labels, out);
  (void)in_sizes; (void)n_in; (void)out_size; (void)ws_size;
}